// Round 1
// 15528.513 us; speedup vs baseline: 1.0228x; 1.0228x over previous
//
#include <hip/hip_runtime.h>
#include <cstdint>
#include <cstddef>

#define H   1024
#define NB  64
#define SL  32
#define VE  32000
#define WLO 3145728   // lo-plane offset inside a [2][3072][1024] weight chunk

typedef unsigned short ushort_t;
typedef __attribute__((ext_vector_type(8))) __bf16    bf16x8;
typedef __attribute__((ext_vector_type(8))) ushort_t  u16x8;
typedef __attribute__((ext_vector_type(4))) float     f32x4;

struct Partial { float v; int i; };

// fc grid: 1000 blocks x 32 vocab rows (was 250 x 128). 4 blocks/CU ->
// 4 waves/SIMD for latency hiding (fc was latency-bound at 10.5% occupancy).
#define FC_BLOCKS 1000
#define FC_ROWS   32      // vocab rows per block
#define FC_TILES  2       // FC_ROWS / 16
#define NPART     (FC_BLOCKS * 2)   // partials per batch row

__device__ __forceinline__ float bf2f(ushort_t u){ return __uint_as_float(((unsigned)u) << 16); }
__device__ __forceinline__ ushort_t f2bf(float f){
    unsigned u = __float_as_uint(f);
    return (ushort_t)((u + 0x7FFFu + ((u >> 16) & 1u)) >> 16);   // RTNE
}
__device__ __forceinline__ bf16x8 ldb8(const ushort_t* p){ return *reinterpret_cast<const bf16x8*>(p); }
__device__ __forceinline__ f32x4 MF(bf16x8 a, bf16x8 b, f32x4 c){
    return __builtin_amdgcn_mfma_f32_16x16x32_bf16(a, b, c, 0, 0, 0);
}
__device__ __forceinline__ float sigmf(float x){
    if (x >= 0.f){ float z = expf(-x); return 1.f / (1.f + z); }
    float z = expf(x); return z / (1.f + z);
}
// split 8 contiguous f32 into bf16 hi + lo fragments (RTNE both)
__device__ __forceinline__ void split8f(const float* p, bf16x8& h8, bf16x8& l8){
    float4 a = *reinterpret_cast<const float4*>(p);
    float4 b = *reinterpret_cast<const float4*>(p + 4);
    float w[8] = {a.x,a.y,a.z,a.w,b.x,b.y,b.z,b.w};
    u16x8 hu, lu;
    #pragma unroll
    for (int i = 0; i < 8; ++i){
        ushort_t hh = f2bf(w[i]);
        hu[i] = hh;
        lu[i] = f2bf(w[i] - bf2f(hh));
    }
    h8 = __builtin_bit_cast(bf16x8, hu);
    l8 = __builtin_bit_cast(bf16x8, lu);
}
__device__ __forceinline__ bf16x8 hi8f(const float* p){
    float4 a = *reinterpret_cast<const float4*>(p);
    float4 b = *reinterpret_cast<const float4*>(p + 4);
    float w[8] = {a.x,a.y,a.z,a.w,b.x,b.y,b.z,b.w};
    u16x8 hu;
    #pragma unroll
    for (int i = 0; i < 8; ++i) hu[i] = f2bf(w[i]);
    return __builtin_bit_cast(bf16x8, hu);
}
// top-2 insert (value desc, tie -> lower index)
__device__ __forceinline__ void t2ins(float& v1, int& i1, float& v2, int& i2, float w, int j){
    if (w > v1 || (w == v1 && j < i1)){ v2 = v1; i2 = i1; v1 = w; i1 = j; }
    else if (w > v2 || (w == v2 && j < i2)){ v2 = w; i2 = j; }
}

// ---------------------------------------------------------------------------
// prep kernels
// ---------------------------------------------------------------------------
__global__ __launch_bounds__(256) void prep_split(const float* __restrict__ src,
    ushort_t* __restrict__ dst, int n4, int lo_off)
{
    int gid = blockIdx.x * 256 + threadIdx.x;
    if (gid >= n4) return;
    float4 v = reinterpret_cast<const float4*>(src)[gid];
    ushort4 h, l;
    h.x = f2bf(v.x); l.x = f2bf(v.x - bf2f(h.x));
    h.y = f2bf(v.y); l.y = f2bf(v.y - bf2f(h.y));
    h.z = f2bf(v.z); l.z = f2bf(v.z - bf2f(h.z));
    h.w = f2bf(v.w); l.w = f2bf(v.w - bf2f(h.w));
    reinterpret_cast<ushort4*>(dst)[gid] = h;
    reinterpret_cast<ushort4*>(dst + lo_off)[gid] = l;
}

__global__ __launch_bounds__(256) void prep_fcwhi(const float* __restrict__ src,
    ushort_t* __restrict__ dst, int n4)
{
    int gid = blockIdx.x * 256 + threadIdx.x;
    if (gid >= n4) return;
    float4 v = reinterpret_cast<const float4*>(src)[gid];
    ushort4 h;
    h.x = f2bf(v.x); h.y = f2bf(v.y); h.z = f2bf(v.z); h.w = f2bf(v.w);
    reinterpret_cast<ushort4*>(dst)[gid] = h;
}

__global__ __launch_bounds__(256) void prep_gather(const int* __restrict__ x,
    const float* __restrict__ fr_emb, ushort_t* __restrict__ A_enc)
{
    int gid = blockIdx.x * 256 + threadIdx.x;    // 524288
    int row = gid >> 8;                          // t*64+b, 2048 rows
    int c4  = (gid & 255) * 4;
    int t = row >> 6, b = row & 63;
    int tokn = x[b * SL + t];
    float4 v = *reinterpret_cast<const float4*>(fr_emb + (size_t)tokn * H + c4);
    ushort4 h, l;
    h.x = f2bf(v.x); l.x = f2bf(v.x - bf2f(h.x));
    h.y = f2bf(v.y); l.y = f2bf(v.y - bf2f(h.y));
    h.z = f2bf(v.z); l.z = f2bf(v.z - bf2f(h.z));
    h.w = f2bf(v.w); l.w = f2bf(v.w - bf2f(h.w));
    ushort_t* base = A_enc + (size_t)t * 131072 + (size_t)b * H + c4;
    *reinterpret_cast<ushort4*>(base) = h;
    *reinterpret_cast<ushort4*>(base + 65536) = l;
}

__global__ __launch_bounds__(256) void prep_zero(ushort_t* hA0, ushort_t* hA1,
                                                 float* h0f, float* h1f)
{
    int gid = blockIdx.x * 256 + threadIdx.x;    // 16384
    uint4 z = {0,0,0,0};
    reinterpret_cast<uint4*>(hA0)[gid] = z;
    reinterpret_cast<uint4*>(hA1)[gid] = z;
    reinterpret_cast<uint4*>(h0f)[gid] = z;
    reinterpret_cast<uint4*>(h1f)[gid] = z;
}

// ---------------------------------------------------------------------------
// gru_step: one GRU cell for 64 batch rows. grid 64 (16-wide j tiles), 256 thr.
// A1: hi/lo planes (A1p) or f32 embedding gather (emb+tok). A2: hi/lo planes.
// Weights: pre-split planes (Wihp/Whhp) or on-the-fly split from f32.
// 3-MFMA scheme per gate-side: ah*wh + al*wh + ah*wl   (al*wl negligible)
// ---------------------------------------------------------------------------
__global__ __launch_bounds__(256) void gru_step(
    const ushort_t* __restrict__ A1p,
    const float* __restrict__ emb, const int* __restrict__ tok, int tok_zero,
    const ushort_t* __restrict__ A2p,
    const ushort_t* __restrict__ Wihp, const ushort_t* __restrict__ Whhp,
    const float* __restrict__ Wihf, const float* __restrict__ Whhf,
    const float* __restrict__ bih, const float* __restrict__ bhh,
    const float* __restrict__ h_prev, float* __restrict__ h_out,
    ushort_t* __restrict__ hA_out, ushort_t* __restrict__ hilo_extra,
    float* __restrict__ f32_extra, int f32_stride)
{
    const int tid = threadIdx.x, lane = tid & 63, wv = tid >> 6;
    const int quad = lane >> 4, l16 = lane & 15;
    const int j0 = blockIdx.x * 16, m = wv * 16 + l16, jr = j0 + l16;

    f32x4 accr = {0,0,0,0}, accz = {0,0,0,0}, acci = {0,0,0,0}, acch = {0,0,0,0};

    const float* embrow = nullptr;
    const ushort_t *ah_row = nullptr, *al_row = nullptr;
    if (A1p){ ah_row = A1p + (size_t)m * H; al_row = ah_row + 64 * H; }
    else    { int t = tok_zero ? 0 : tok[m]; embrow = emb + (size_t)t * H; }

    // ---- phase A: input-side (Wih) ----
    {
        const ushort_t *wrp = nullptr, *wzp = nullptr, *wnp = nullptr;
        const float *wrf = nullptr, *wzf = nullptr, *wnf = nullptr;
        if (Wihp){
            wrp = Wihp + (size_t)jr * H;
            wzp = Wihp + (size_t)(H + jr) * H;
            wnp = Wihp + (size_t)(2 * H + jr) * H;
        } else {
            wrf = Wihf + (size_t)jr * H;
            wzf = Wihf + (size_t)(H + jr) * H;
            wnf = Wihf + (size_t)(2 * H + jr) * H;
        }
        for (int kk = 0; kk < H; kk += 32){
            int ko = kk + quad * 8;
            bf16x8 ah, al;
            if (A1p){ ah = ldb8(ah_row + ko); al = ldb8(al_row + ko); }
            else      split8f(embrow + ko, ah, al);
            bf16x8 wrh, wrl, wzh, wzl, wnh, wnl;
            if (Wihp){
                wrh = ldb8(wrp + ko); wrl = ldb8(wrp + WLO + ko);
                wzh = ldb8(wzp + ko); wzl = ldb8(wzp + WLO + ko);
                wnh = ldb8(wnp + ko); wnl = ldb8(wnp + WLO + ko);
            } else {
                split8f(wrf + ko, wrh, wrl);
                split8f(wzf + ko, wzh, wzl);
                split8f(wnf + ko, wnh, wnl);
            }
            accr = MF(ah, wrh, accr); accr = MF(al, wrh, accr); accr = MF(ah, wrl, accr);
            accz = MF(ah, wzh, accz); accz = MF(al, wzh, accz); accz = MF(ah, wzl, accz);
            acci = MF(ah, wnh, acci); acci = MF(al, wnh, acci); acci = MF(ah, wnl, acci);
        }
    }
    // ---- phase B: hidden-side (Whh) ----
    {
        const ushort_t* a2h = A2p + (size_t)m * H;
        const ushort_t* a2l = a2h + 64 * H;
        const ushort_t *wrp = nullptr, *wzp = nullptr, *wnp = nullptr;
        const float *wrf = nullptr, *wzf = nullptr, *wnf = nullptr;
        if (Whhp){
            wrp = Whhp + (size_t)jr * H;
            wzp = Whhp + (size_t)(H + jr) * H;
            wnp = Whhp + (size_t)(2 * H + jr) * H;
        } else {
            wrf = Whhf + (size_t)jr * H;
            wzf = Whhf + (size_t)(H + jr) * H;
            wnf = Whhf + (size_t)(2 * H + jr) * H;
        }
        for (int kk = 0; kk < H; kk += 32){
            int ko = kk + quad * 8;
            bf16x8 ah = ldb8(a2h + ko), al = ldb8(a2l + ko);
            bf16x8 wrh, wrl, wzh, wzl, wnh, wnl;
            if (Whhp){
                wrh = ldb8(wrp + ko); wrl = ldb8(wrp + WLO + ko);
                wzh = ldb8(wzp + ko); wzl = ldb8(wzp + WLO + ko);
                wnh = ldb8(wnp + ko); wnl = ldb8(wnp + WLO + ko);
            } else {
                split8f(wrf + ko, wrh, wrl);
                split8f(wzf + ko, wzh, wzl);
                split8f(wnf + ko, wnh, wnl);
            }
            accr = MF(ah, wrh, accr); accr = MF(al, wrh, accr); accr = MF(ah, wrl, accr);
            accz = MF(ah, wzh, accz); accz = MF(al, wzh, accz); accz = MF(ah, wzl, accz);
            acch = MF(ah, wnh, acch); acch = MF(al, wnh, acch); acch = MF(ah, wnl, acch);
        }
    }

    // ---- epilogue: gates (f32, exact f32 biases), write h + hi/lo planes ----
    const float bir = bih[jr],         bhr = bhh[jr];
    const float biz = bih[H + jr],     bhz = bhh[H + jr];
    const float bin = bih[2 * H + jr], bhn = bhh[2 * H + jr];
    #pragma unroll
    for (int reg = 0; reg < 4; ++reg){
        int b = wv * 16 + quad * 4 + reg;      // D row = quad*4+reg in tile
        float r  = sigmf(accr[reg] + bir + bhr);
        float z  = sigmf(accz[reg] + biz + bhz);
        float n  = tanhf(acci[reg] + bin + r * (acch[reg] + bhn));
        float hp = h_prev[b * H + jr];
        float hv = (1.f - z) * n + z * hp;
        h_out[b * H + jr] = hv;
        ushort_t hi = f2bf(hv);
        ushort_t lo = f2bf(hv - bf2f(hi));
        hA_out[b * H + jr] = hi; hA_out[64 * H + b * H + jr] = lo;
        if (hilo_extra){ hilo_extra[b * H + jr] = hi; hilo_extra[64 * H + b * H + jr] = lo; }
        if (f32_extra){ f32_extra[(size_t)b * f32_stride + jr] = hv; }
    }
}

// ---------------------------------------------------------------------------
__global__ __launch_bounds__(256) void vnorm_kernel(const float* __restrict__ enc_out,
                                                    float* __restrict__ v_norm)
{
    const int b = blockIdx.x, tid = threadIdx.x, lane = tid & 63, wv = tid >> 6;
    for (int s = wv; s < SL; s += 4){
        const float* e = enc_out + (size_t)b * SL * H + (size_t)s * H;
        float d = 0.f;
        for (int k = lane; k < H; k += 64){ float v = e[k]; d += v * v; }
        #pragma unroll
        for (int msk = 1; msk < 64; msk <<= 1) d += __shfl_xor(d, msk);
        if (lane == 0) v_norm[b * SL + s] = fmaxf(sqrtf(d), 1e-8f);
    }
}

// ---------------------------------------------------------------------------
// attention: per batch row. scores -> softmax -> context. Writes attention
// weights (f32 output 2), the fc A matrix as bf16 hi/lo planes, and f32 copy.
// ---------------------------------------------------------------------------
__global__ __launch_bounds__(256) void attn_kernel(
    const float* __restrict__ out_f32, const float* __restrict__ enc_out,
    const float* __restrict__ v_norm, ushort_t* __restrict__ outa,
    float* __restrict__ outa_f, float* __restrict__ attn_out, int step)
{
    const int b = blockIdx.x, tid = threadIdx.x, lane = tid & 63, wv = tid >> 6;
    __shared__ float o_lds[H];
    __shared__ float red[256];
    __shared__ float sc[SL];
    __shared__ float wts[SL];

    float p = 0.f;
    for (int k = tid; k < H; k += 256){ float v = out_f32[b * H + k]; o_lds[k] = v; p += v * v; }
    red[tid] = p; __syncthreads();
    for (int s = 128; s > 0; s >>= 1){ if (tid < s) red[tid] += red[tid + s]; __syncthreads(); }
    float qn = fmaxf(sqrtf(red[0]), 1e-8f);

    for (int s = wv; s < SL; s += 4){
        const float* e = enc_out + (size_t)b * SL * H + (size_t)s * H;
        float d = 0.f;
        for (int k = lane; k < H; k += 64) d += e[k] * o_lds[k];
        #pragma unroll
        for (int msk = 1; msk < 64; msk <<= 1) d += __shfl_xor(d, msk);
        if (lane == 0) sc[s] = d / (v_norm[b * SL + s] * qn);
    }
    __syncthreads();
    if (tid == 0){
        float mx = sc[0];
        for (int s = 1; s < SL; ++s) mx = fmaxf(mx, sc[s]);
        float sum = 0.f;
        for (int s = 0; s < SL; ++s){ float e = expf(sc[s] - mx); wts[s] = e; sum += e; }
        for (int s = 0; s < SL; ++s){
            float w = wts[s] / sum; wts[s] = w;
            attn_out[b * (SL * SL) + step * SL + s] = w;
        }
    }
    __syncthreads();
    for (int k = tid; k < H; k += 256){
        float a = 0.f;
        const float* e = enc_out + (size_t)b * SL * H + k;
        #pragma unroll
        for (int s = 0; s < SL; ++s) a += wts[s] * e[(size_t)s * H];
        float ov = o_lds[k];
        ushort_t oh = f2bf(ov);
        outa[b * 2048 + k]          = oh;
        outa[131072 + b * 2048 + k] = f2bf(ov - bf2f(oh));
        ushort_t ah = f2bf(a);
        outa[b * 2048 + H + k]          = ah;
        outa[131072 + b * 2048 + H + k] = f2bf(a - bf2f(ah));
        outa_f[b * 2048 + k]     = ov;
        outa_f[b * 2048 + H + k] = a;
    }
}

// ---------------------------------------------------------------------------
// fc: logits = [out|a] @ fcW.T + fcb. FC_BLOCKS blocks x FC_ROWS vocab rows.
// A hi/lo planes x W hi plane (2 MFMAs). Writes f32 logits (output 0) and
// per-block top-2 partials for the exact argmax recheck.
// Grid raised 250->1000 (32 rows/block): fc was latency-bound at 1 block/CU
// (Occupancy 10.5%, all pipes <5%); 4 blocks/CU gives 4 waves/SIMD to hide
// the ~900cy HBM latency of the 4KB-strided fcW row loads.
// ---------------------------------------------------------------------------
__global__ __launch_bounds__(256) void fc_kernel(
    const ushort_t* __restrict__ outa, const ushort_t* __restrict__ fcWhi,
    const float* __restrict__ fcWf, const float* __restrict__ fcb,
    float* __restrict__ vec_out, int step, Partial* __restrict__ parts)
{
    const int tid = threadIdx.x, lane = tid & 63, wv = tid >> 6;
    const int quad = lane >> 4, l16 = lane & 15;
    const int n0 = blockIdx.x * FC_ROWS;
    f32x4 acc[FC_TILES];
    #pragma unroll
    for (int t = 0; t < FC_TILES; ++t) acc[t] = (f32x4){0,0,0,0};
    const ushort_t* arow = outa + (size_t)(wv * 16 + l16) * 2048;

    for (int kk = 0; kk < 2048; kk += 32){
        int ko = kk + quad * 8;
        bf16x8 ah = ldb8(arow + ko);
        bf16x8 al = ldb8(arow + 131072 + ko);
        #pragma unroll
        for (int t = 0; t < FC_TILES; ++t){
            int n = n0 + t * 16 + l16;
            bf16x8 bb = fcWhi ? ldb8(fcWhi + (size_t)n * 2048 + ko)
                              : hi8f(fcWf + (size_t)n * 2048 + ko);
            acc[t] = MF(ah, bb, acc[t]);
            acc[t] = MF(al, bb, acc[t]);
        }
    }
    #pragma unroll
    for (int reg = 0; reg < 4; ++reg){
        int b = wv * 16 + quad * 4 + reg;
        float v1 = -3.4e38f, v2 = -3.4e38f; int i1 = 0x7FFFFFFF, i2 = 0x7FFFFFFF;
        #pragma unroll
        for (int t = 0; t < FC_TILES; ++t){
            int n = n0 + t * 16 + l16;
            float v = acc[t][reg] + fcb[n];
            vec_out[(size_t)b * 1024000 + (size_t)step * 32000 + n] = v;
            t2ins(v1, i1, v2, i2, v, n);
        }
        #pragma unroll
        for (int msk = 1; msk <= 8; msk <<= 1){
            float w1 = __shfl_xor(v1, msk); int j1 = __shfl_xor(i1, msk);
            float w2 = __shfl_xor(v2, msk); int j2 = __shfl_xor(i2, msk);
            t2ins(v1, i1, v2, i2, w1, j1);
            t2ins(v1, i1, v2, i2, w2, j2);
        }
        if (l16 == 0){
            Partial* pp = parts + ((size_t)b * FC_BLOCKS + blockIdx.x) * 2;
            pp[0].v = v1; pp[0].i = i1;
            pp[1].v = v2; pp[1].i = i2;
        }
    }
}

// ---------------------------------------------------------------------------
// pick: per batch row, approx top-8 of NPART partials, exact f64 recheck
// against f32 fcW/fcb, write argmax token (tie -> lowest index).
// ---------------------------------------------------------------------------
__global__ __launch_bounds__(256) void pick_kernel(
    const Partial* __restrict__ parts, const float* __restrict__ outa_f,
    const float* __restrict__ fcWf, const float* __restrict__ fcb,
    int* __restrict__ tok)
{
    const int b = blockIdx.x, tid = threadIdx.x;
    __shared__ float pv[2048]; __shared__ int pi[2048];
    __shared__ float rv[256]; __shared__ int ri[256];
    __shared__ int cand[8];
    for (int s = tid; s < 2048; s += 256){
        if (s < NPART){ Partial pp = parts[(size_t)b * NPART + s]; pv[s] = pp.v; pi[s] = pp.i; }
        else { pv[s] = -3.4e38f; pi[s] = 0x7FFFFFFF; }
    }
    __syncthreads();
    for (int r = 0; r < 8; ++r){
        float bvv = -3.4e38f; int bs = tid;
        for (int s = tid; s < 2048; s += 256){
            if (pv[s] > bvv){ bvv = pv[s]; bs = s; }
        }
        rv[tid] = bvv; ri[tid] = bs;
        __syncthreads();
        for (int st = 128; st > 0; st >>= 1){
            if (tid < st && rv[tid + st] > rv[tid]){ rv[tid] = rv[tid + st]; ri[tid] = ri[tid + st]; }
            __syncthreads();
        }
        if (tid == 0){ int sl = ri[0]; cand[r] = pi[sl]; pv[sl] = -3.4e38f; }
        __syncthreads();
    }
    __shared__ double dred[256];
    __shared__ double dbest; __shared__ int dbesti;
    if (tid == 0){ dbest = -1e300; dbesti = 0x7FFFFFFF; }
    __syncthreads();
    for (int c = 0; c < 8; ++c){
        int n = cand[c];
        const float* w = fcWf + (size_t)n * 2048;
        const float* a = outa_f + (size_t)b * 2048;
        double d = 0.0;
        for (int k = tid; k < 2048; k += 256) d += (double)a[k] * (double)w[k];
        dred[tid] = d; __syncthreads();
        for (int st = 128; st > 0; st >>= 1){
            if (tid < st) dred[tid] += dred[tid + st];
            __syncthreads();
        }
        if (tid == 0){
            double tot = dred[0] + (double)fcb[n];
            if (tot > dbest || (tot == dbest && n < dbesti)){ dbest = tot; dbesti = n; }
        }
        __syncthreads();
    }
    if (tid == 0) tok[b] = dbesti;
}

// ---------------------------------------------------------------------------
__global__ __launch_bounds__(256) void fin_kernel(const float* __restrict__ h0f,
                                                  const float* __restrict__ h1f,
                                                  float* __restrict__ dst)
{
    int gid = blockIdx.x * 256 + threadIdx.x;     // 131072
    dst[gid] = (gid < 65536) ? h0f[gid] : h1f[gid - 65536];
}

// ---------------------------------------------------------------------------
extern "C" void kernel_launch(void* const* d_in, const int* in_sizes, int n_in,
                              void* d_out, int out_size, void* d_ws, size_t ws_size,
                              hipStream_t stream)
{
    (void)in_sizes; (void)n_in; (void)out_size;
    const int*   x      = (const int*)d_in[0];
    const float* fr_emb = (const float*)d_in[1];
    const float* en_emb = (const float*)d_in[2];
    const float* eWih   = (const float*)d_in[3];
    const float* eWhh   = (const float*)d_in[4];
    const float* ebih   = (const float*)d_in[5];
    const float* ebhh   = (const float*)d_in[6];
    const float* dWih   = (const float*)d_in[7];
    const float* dWhh   = (const float*)d_in[8];
    const float* dbih   = (const float*)d_in[9];
    const float* dbhh   = (const float*)d_in[10];
    const float* fcWf   = (const float*)d_in[11];
    const float* fcb    = (const float*)d_in[12];
    float* out = (float*)d_out;

    // ---- workspace layout (cursor) ----
    char* ws = (char*)d_ws;
    const size_t GRUW_BYTES = 100663296;      // 8 chunks x [2][3072][1024] bf16
    // small region sizes (bytes)
    const size_t SZ_AENC = 8388608, SZ_SEQ0 = 8388608, SZ_HA = 524288,
                 SZ_OUTA = 524288, SZ_ENC = 8388608, SZ_HF = 524288,
                 SZ_OUTAF = 524288, SZ_VN = 8192, SZ_PART = 1048576, SZ_TOK = 4096;
    const size_t SMALL_TOTAL = SZ_AENC + SZ_SEQ0 + 2*SZ_HA + SZ_OUTA + SZ_ENC +
                               2*SZ_HF + SZ_OUTAF + SZ_VN + SZ_PART + SZ_TOK;  // ~29 MB
    bool gru_pre = (ws_size >= GRUW_BYTES + SMALL_TOTAL);
    size_t cur = 0;
    ushort_t* gruW = nullptr;
    if (gru_pre){ gruW = (ushort_t*)(ws + cur); cur += GRUW_BYTES; }
    ushort_t* A_enc = (ushort_t*)(ws + cur); cur += SZ_AENC;
    ushort_t* seq0  = (ushort_t*)(ws + cur); cur += SZ_SEQ0;
    ushort_t* hA0   = (ushort_t*)(ws + cur); cur += SZ_HA;
    ushort_t* hA1   = (ushort_t*)(ws + cur); cur += SZ_HA;
    ushort_t* outa  = (ushort_t*)(ws + cur); cur += SZ_OUTA;
    float*    enc_o = (float*)   (ws + cur); cur += SZ_ENC;
    float*    h0f   = (float*)   (ws + cur); cur += SZ_HF;
    float*    h1f   = (float*)   (ws + cur); cur += SZ_HF;
    float*    outaf = (float*)   (ws + cur); cur += SZ_OUTAF;
    float*    v_nrm = (float*)   (ws + cur); cur += SZ_VN;
    Partial*  parts = (Partial*) (ws + cur); cur += SZ_PART;
    int*      tok   = (int*)     (ws + cur); cur += SZ_TOK;
    ushort_t* fcWhi = nullptr;
    if (cur + 131072000 <= ws_size){ fcWhi = (ushort_t*)(ws + cur); cur += 131072000; }

    const size_t CH = 6291456;               // ushorts per weight chunk (2 planes)
    const size_t LYW = 3145728;              // f32 layer stride of (3072,1024)
    const size_t LYB = 3072;

    // ---- prep ----
    if (gru_pre){
        const float* srcs[4] = {eWih, eWhh, dWih, dWhh};
        for (int tns = 0; tns < 4; ++tns)
            for (int l = 0; l < 2; ++l)
                prep_split<<<3072, 256, 0, stream>>>(srcs[tns] + (size_t)l * LYW,
                    gruW + (size_t)(tns * 2 + l) * CH, 786432, WLO);
    }
    if (fcWhi) prep_fcwhi<<<64000, 256, 0, stream>>>(fcWf, fcWhi, 16384000);
    prep_gather<<<2048, 256, 0, stream>>>(x, fr_emb, A_enc);
    prep_zero<<<64, 256, 0, stream>>>(hA0, hA1, h0f, h1f);

    auto WP = [&](int tns, int l) -> const ushort_t* {
        return gru_pre ? gruW + (size_t)(tns * 2 + l) * CH : nullptr;
    };

    // ---- encoder layer 0 ----
    for (int t = 0; t < 32; ++t){
        gru_step<<<64, 256, 0, stream>>>(
            A_enc + (size_t)t * 131072, nullptr, nullptr, 0,
            hA0 + (size_t)(t & 1) * 131072,
            WP(0,0), WP(1,0), eWih, eWhh, ebih, ebhh,
            h0f + (size_t)(t & 1) * 65536, h0f + (size_t)((t + 1) & 1) * 65536,
            hA0 + (size_t)((t + 1) & 1) * 131072,
            seq0 + (size_t)t * 131072, (float*)nullptr, 0);
    }
    // ---- encoder layer 1 ----
    for (int t = 0; t < 32; ++t){
        gru_step<<<64, 256, 0, stream>>>(
            seq0 + (size_t)t * 131072, nullptr, nullptr, 0,
            hA1 + (size_t)(t & 1) * 131072,
            WP(0,1), WP(1,1), eWih + LYW, eWhh + LYW, ebih + LYB, ebhh + LYB,
            h1f + (size_t)(t & 1) * 65536, h1f + (size_t)((t + 1) & 1) * 65536,
            hA1 + (size_t)((t + 1) & 1) * 131072,
            (ushort_t*)nullptr, enc_o + (size_t)t * H, SL * H);
    }
    vnorm_kernel<<<64, 256, 0, stream>>>(enc_o, v_nrm);

    // ---- greedy decoder ----
    for (int i = 0; i < 32; ++i){
        int p0 = i & 1, p1 = (i + 1) & 1;
        gru_step<<<64, 256, 0, stream>>>(                  // layer 0, emb gather
            (const ushort_t*)nullptr, en_emb, tok, (i == 0) ? 1 : 0,
            hA0 + (size_t)p0 * 131072,
            WP(2,0), WP(3,0), dWih, dWhh, dbih, dbhh,
            h0f + (size_t)p0 * 65536, h0f + (size_t)p1 * 65536,
            hA0 + (size_t)p1 * 131072,
            (ushort_t*)nullptr, (float*)nullptr, 0);
        gru_step<<<64, 256, 0, stream>>>(                  // layer 1
            hA0 + (size_t)p1 * 131072, nullptr, nullptr, 0,
            hA1 + (size_t)p0 * 131072,
            WP(2,1), WP(3,1), dWih + LYW, dWhh + LYW, dbih + LYB, dbhh + LYB,
            h1f + (size_t)p0 * 65536, h1f + (size_t)p1 * 65536,
            hA1 + (size_t)p1 * 131072,
            (ushort_t*)nullptr, (float*)nullptr, 0);
        attn_kernel<<<64, 256, 0, stream>>>(
            h1f + (size_t)p1 * 65536, enc_o, v_nrm, outa, outaf,
            out + 65667072u, i);
        fc_kernel<<<FC_BLOCKS, 256, 0, stream>>>(
            outa, fcWhi, fcWf, fcb, out, i, parts);
        if (i < 31)
            pick_kernel<<<64, 256, 0, stream>>>(parts, outaf, fcWf, fcb, tok);
    }
    fin_kernel<<<512, 256, 0, stream>>>(h0f, h1f, out + 65536000u);
}

// Round 2
// 9707.022 us; speedup vs baseline: 1.6363x; 1.5997x over previous
//
#include <hip/hip_runtime.h>
#include <cstdint>
#include <cstddef>

#define H   1024
#define NB  64
#define SL  32
#define VE  32000
#define WLO 3145728   // lo-plane offset inside a [2][3072][1024] weight chunk

typedef unsigned short ushort_t;
typedef __attribute__((ext_vector_type(8))) __bf16    bf16x8;
typedef __attribute__((ext_vector_type(8))) ushort_t  u16x8;
typedef __attribute__((ext_vector_type(4))) ushort_t  u16x4;
typedef __attribute__((ext_vector_type(4))) float     f32x4;

struct Partial { float v; int i; };

// fc grid: 1000 blocks x 32 vocab rows. 4 blocks/CU (occupancy fix, round 0).
#define FC_BLOCKS 1000
#define FC_ROWS   32      // vocab rows per block
#define FC_TILES  2       // FC_ROWS / 16
#define NPART     (FC_BLOCKS * 2)   // partials per batch row

#define PSTRIDE 196608    // 64*3072 floats: kc-plane stride in Pi/Ph partials

__device__ __forceinline__ float bf2f(ushort_t u){ return __uint_as_float(((unsigned)u) << 16); }
__device__ __forceinline__ ushort_t f2bf(float f){
    unsigned u = __float_as_uint(f);
    return (ushort_t)((u + 0x7FFFu + ((u >> 16) & 1u)) >> 16);   // RTNE
}
__device__ __forceinline__ bf16x8 ldb8(const ushort_t* p){ return *reinterpret_cast<const bf16x8*>(p); }
__device__ __forceinline__ f32x4 MF(bf16x8 a, bf16x8 b, f32x4 c){
    return __builtin_amdgcn_mfma_f32_16x16x32_bf16(a, b, c, 0, 0, 0);
}
__device__ __forceinline__ float sigmf(float x){
    if (x >= 0.f){ float z = expf(-x); return 1.f / (1.f + z); }
    float z = expf(x); return z / (1.f + z);
}
// split 8 contiguous f32 into bf16 hi + lo fragments (RTNE both)
__device__ __forceinline__ void split8f(const float* p, bf16x8& h8, bf16x8& l8){
    float4 a = *reinterpret_cast<const float4*>(p);
    float4 b = *reinterpret_cast<const float4*>(p + 4);
    float w[8] = {a.x,a.y,a.z,a.w,b.x,b.y,b.z,b.w};
    u16x8 hu, lu;
    #pragma unroll
    for (int i = 0; i < 8; ++i){
        ushort_t hh = f2bf(w[i]);
        hu[i] = hh;
        lu[i] = f2bf(w[i] - bf2f(hh));
    }
    h8 = __builtin_bit_cast(bf16x8, hu);
    l8 = __builtin_bit_cast(bf16x8, lu);
}
__device__ __forceinline__ bf16x8 hi8f(const float* p){
    float4 a = *reinterpret_cast<const float4*>(p);
    float4 b = *reinterpret_cast<const float4*>(p + 4);
    float w[8] = {a.x,a.y,a.z,a.w,b.x,b.y,b.z,b.w};
    u16x8 hu;
    #pragma unroll
    for (int i = 0; i < 8; ++i) hu[i] = f2bf(w[i]);
    return __builtin_bit_cast(bf16x8, hu);
}
// top-2 insert (value desc, tie -> lower index)
__device__ __forceinline__ void t2ins(float& v1, int& i1, float& v2, int& i2, float w, int j){
    if (w > v1 || (w == v1 && j < i1)){ v2 = v1; i2 = i1; v1 = w; i1 = j; }
    else if (w > v2 || (w == v2 && j < i2)){ v2 = w; i2 = j; }
}
__device__ __forceinline__ f32x4 add4(f32x4 a, f32x4 b){
    f32x4 r; r[0]=a[0]+b[0]; r[1]=a[1]+b[1]; r[2]=a[2]+b[2]; r[3]=a[3]+b[3]; return r;
}
__device__ __forceinline__ f32x4 ld4(const float* p){ return *reinterpret_cast<const f32x4*>(p); }

// ---------------------------------------------------------------------------
// prep kernels
// ---------------------------------------------------------------------------
__global__ __launch_bounds__(256) void prep_split(const float* __restrict__ src,
    ushort_t* __restrict__ dst, int n4, int lo_off)
{
    int gid = blockIdx.x * 256 + threadIdx.x;
    if (gid >= n4) return;
    float4 v = reinterpret_cast<const float4*>(src)[gid];
    ushort4 h, l;
    h.x = f2bf(v.x); l.x = f2bf(v.x - bf2f(h.x));
    h.y = f2bf(v.y); l.y = f2bf(v.y - bf2f(h.y));
    h.z = f2bf(v.z); l.z = f2bf(v.z - bf2f(h.z));
    h.w = f2bf(v.w); l.w = f2bf(v.w - bf2f(h.w));
    reinterpret_cast<ushort4*>(dst)[gid] = h;
    reinterpret_cast<ushort4*>(dst + lo_off)[gid] = l;
}

__global__ __launch_bounds__(256) void prep_fcwhi(const float* __restrict__ src,
    ushort_t* __restrict__ dst, int n4)
{
    int gid = blockIdx.x * 256 + threadIdx.x;
    if (gid >= n4) return;
    float4 v = reinterpret_cast<const float4*>(src)[gid];
    ushort4 h;
    h.x = f2bf(v.x); h.y = f2bf(v.y); h.z = f2bf(v.z); h.w = f2bf(v.w);
    reinterpret_cast<ushort4*>(dst)[gid] = h;
}

__global__ __launch_bounds__(256) void prep_gather(const int* __restrict__ x,
    const float* __restrict__ fr_emb, ushort_t* __restrict__ A_enc)
{
    int gid = blockIdx.x * 256 + threadIdx.x;    // 524288
    int row = gid >> 8;                          // t*64+b, 2048 rows
    int c4  = (gid & 255) * 4;
    int t = row >> 6, b = row & 63;
    int tokn = x[b * SL + t];
    float4 v = *reinterpret_cast<const float4*>(fr_emb + (size_t)tokn * H + c4);
    ushort4 h, l;
    h.x = f2bf(v.x); l.x = f2bf(v.x - bf2f(h.x));
    h.y = f2bf(v.y); l.y = f2bf(v.y - bf2f(h.y));
    h.z = f2bf(v.z); l.z = f2bf(v.z - bf2f(h.z));
    h.w = f2bf(v.w); l.w = f2bf(v.w - bf2f(h.w));
    ushort_t* base = A_enc + (size_t)t * 131072 + (size_t)b * H + c4;
    *reinterpret_cast<ushort4*>(base) = h;
    *reinterpret_cast<ushort4*>(base + 65536) = l;
}

__global__ __launch_bounds__(256) void prep_zero(ushort_t* hA0, ushort_t* hA1,
                                                 float* h0f, float* h1f)
{
    int gid = blockIdx.x * 256 + threadIdx.x;    // 16384
    uint4 z = {0,0,0,0};
    reinterpret_cast<uint4*>(hA0)[gid] = z;
    reinterpret_cast<uint4*>(hA1)[gid] = z;
    reinterpret_cast<uint4*>(h0f)[gid] = z;
    reinterpret_cast<uint4*>(h1f)[gid] = z;
}

// ---------------------------------------------------------------------------
// gru_gemm: one GRU cell's two GEMMs, full-chip. Grid 256 = 64 j-tiles x
// 2 sides (input/hidden) x 2 K-chunks; 1 block/CU. Each block async-stages
// its 96 KB weight slice (3 gates x 16 rows x hi/lo x 512 K) into LDS via
// 96 global_load_lds dwordx4 row-segments (24 per wave -> ~24 KB in flight
// per wave: fixes the outstanding-bytes starvation that held gru_step at
// ~190 GB/s). XOR-swizzle (r&7)<<4 applied to the GLOBAL source and the
// ds_read address (both-sides-or-neither) -> bank-balanced ds_read_b128.
// Writes f32 partials Pi/Ph[kc][64][3072]; gate_fin combines.
// ---------------------------------------------------------------------------
__global__ __launch_bounds__(256) void gru_gemm(
    const ushort_t* __restrict__ A1p,            // input-side A hi/lo planes (or null -> emb mode)
    const float* __restrict__ emb, const int* __restrict__ tok, int tok_zero,
    const ushort_t* __restrict__ A2p,            // hidden-side A hi/lo planes
    const ushort_t* __restrict__ Wihp, const ushort_t* __restrict__ Whhp,
    float* __restrict__ Pi, float* __restrict__ Ph)
{
    __shared__ __attribute__((aligned(16))) char wlds[98304];   // 96 segs x 1 KB
    const int tid = threadIdx.x, lane = tid & 63, wv = tid >> 6;
    const int quad = lane >> 4, l16 = lane & 15;
    const int bid = blockIdx.x;
    const int jt = bid & 63, side = (bid >> 6) & 1, kc = bid >> 7;
    const ushort_t* W = side ? Whhp : Wihp;

    // ---- async-stage: seg s -> gate g = s>>5, row r = (s&31)>>1, plane p = s&1
    #pragma unroll
    for (int i = 0; i < 24; ++i){
        int s = wv * 24 + i;
        int g = s >> 5, rm = s & 31, r = rm >> 1, p = rm & 1;
        const char* src = (const char*)(W + (size_t)(g * H + jt * 16 + r) * H
                                          + (size_t)p * WLO + kc * 512)
                          + ((lane * 16) ^ ((r & 7) << 4));
        __builtin_amdgcn_global_load_lds(
            (const __attribute__((address_space(1))) void*)src,
            (__attribute__((address_space(3))) void*)(wlds + s * 1024), 16, 0, 0);
    }

    // ---- per-wave A row pointers (batch rows m = wv*16 + l16) ----
    const int m = wv * 16 + l16;
    const bool emode = (!side) && (A1p == nullptr);
    const ushort_t *arh = nullptr, *arl = nullptr;
    const float* embrow = nullptr;
    if (side){ arh = A2p + (size_t)m * H; arl = arh + 64 * H; }
    else if (!emode){ arh = A1p + (size_t)m * H; arl = arh + 64 * H; }
    else { int t = tok_zero ? 0 : tok[m]; embrow = emb + (size_t)t * H; }

    const int swz = (l16 & 7) << 4;
    const char* sb00 = wlds + (l16 * 2) * 1024;          // gate 0 hi
    const char* sb01 = sb00 + 1024;                      // gate 0 lo
    const char* sb10 = wlds + (32 + l16 * 2) * 1024;     // gate 1 hi
    const char* sb11 = sb10 + 1024;
    const char* sb20 = wlds + (64 + l16 * 2) * 1024;     // gate 2 hi
    const char* sb21 = sb20 + 1024;

    __syncthreads();   // drains vmcnt(0): staged data visible

    f32x4 acc0 = {0,0,0,0}, acc1 = {0,0,0,0}, acc2 = {0,0,0,0};
    const int kb = kc * 512;
    #pragma unroll 4
    for (int kk = 0; kk < 512; kk += 32){
        int ko = kb + kk + quad * 8;
        bf16x8 ah, al;
        if (emode) split8f(embrow + ko, ah, al);
        else { ah = ldb8(arh + ko); al = ldb8(arl + ko); }
        int xo = ((kk + quad * 8) * 2) ^ swz;
        bf16x8 w0h = *reinterpret_cast<const bf16x8*>(sb00 + xo);
        bf16x8 w0l = *reinterpret_cast<const bf16x8*>(sb01 + xo);
        bf16x8 w1h = *reinterpret_cast<const bf16x8*>(sb10 + xo);
        bf16x8 w1l = *reinterpret_cast<const bf16x8*>(sb11 + xo);
        bf16x8 w2h = *reinterpret_cast<const bf16x8*>(sb20 + xo);
        bf16x8 w2l = *reinterpret_cast<const bf16x8*>(sb21 + xo);
        acc0 = MF(ah, w0h, acc0); acc0 = MF(al, w0h, acc0); acc0 = MF(ah, w0l, acc0);
        acc1 = MF(ah, w1h, acc1); acc1 = MF(al, w1h, acc1); acc1 = MF(ah, w1l, acc1);
        acc2 = MF(ah, w2h, acc2); acc2 = MF(al, w2h, acc2); acc2 = MF(ah, w2l, acc2);
    }

    // D-tile: col = l16 (j), row = quad*4+reg (batch within wave tile)
    float* P = (side ? Ph : Pi) + (size_t)kc * PSTRIDE;
    #pragma unroll
    for (int reg = 0; reg < 4; ++reg){
        float* pr = P + (size_t)(wv * 16 + quad * 4 + reg) * 3072 + jt * 16 + l16;
        pr[0] = acc0[reg]; pr[1024] = acc1[reg]; pr[2048] = acc2[reg];
    }
}

// ---------------------------------------------------------------------------
// gate_fin: combine Pi/Ph partials -> GRU gates -> h, hi/lo planes, extras.
// Grid 64 (batch row per block), 256 thr x 4 j each.
// ---------------------------------------------------------------------------
__global__ __launch_bounds__(256) void gate_fin(
    const float* __restrict__ Pi, const float* __restrict__ Ph,
    const float* __restrict__ bih, const float* __restrict__ bhh,
    const float* __restrict__ h_prev, float* __restrict__ h_out,
    ushort_t* __restrict__ hA_out, ushort_t* __restrict__ hilo_extra,
    float* __restrict__ f32_extra, int f32_stride)
{
    const int b = blockIdx.x, j4 = threadIdx.x * 4;
    const float* pi0 = Pi + (size_t)b * 3072;
    const float* pi1 = pi0 + PSTRIDE;
    const float* ph0 = Ph + (size_t)b * 3072;
    const float* ph1 = ph0 + PSTRIDE;

    f32x4 gir = add4(ld4(pi0 + j4),        ld4(pi1 + j4));
    f32x4 giz = add4(ld4(pi0 + 1024 + j4), ld4(pi1 + 1024 + j4));
    f32x4 gin = add4(ld4(pi0 + 2048 + j4), ld4(pi1 + 2048 + j4));
    f32x4 ghr = add4(ld4(ph0 + j4),        ld4(ph1 + j4));
    f32x4 ghz = add4(ld4(ph0 + 1024 + j4), ld4(ph1 + 1024 + j4));
    f32x4 ghn = add4(ld4(ph0 + 2048 + j4), ld4(ph1 + 2048 + j4));

    f32x4 bir4 = ld4(bih + j4),        bhr4 = ld4(bhh + j4);
    f32x4 biz4 = ld4(bih + 1024 + j4), bhz4 = ld4(bhh + 1024 + j4);
    f32x4 bin4 = ld4(bih + 2048 + j4), bhn4 = ld4(bhh + 2048 + j4);
    f32x4 hp4  = ld4(h_prev + b * 1024 + j4);

    f32x4 hv4;
    u16x4 hi4, lo4;
    #pragma unroll
    for (int c = 0; c < 4; ++c){
        float r  = sigmf(gir[c] + ghr[c] + bir4[c] + bhr4[c]);
        float z  = sigmf(giz[c] + ghz[c] + biz4[c] + bhz4[c]);
        float n  = tanhf(gin[c] + bin4[c] + r * (ghn[c] + bhn4[c]));
        float hv = (1.f - z) * n + z * hp4[c];
        hv4[c] = hv;
        ushort_t hi = f2bf(hv);
        hi4[c] = hi;
        lo4[c] = f2bf(hv - bf2f(hi));
    }
    *reinterpret_cast<f32x4*>(h_out + b * 1024 + j4) = hv4;
    *reinterpret_cast<u16x4*>(hA_out + b * 1024 + j4) = hi4;
    *reinterpret_cast<u16x4*>(hA_out + 65536 + b * 1024 + j4) = lo4;
    if (hilo_extra){
        *reinterpret_cast<u16x4*>(hilo_extra + b * 1024 + j4) = hi4;
        *reinterpret_cast<u16x4*>(hilo_extra + 65536 + b * 1024 + j4) = lo4;
    }
    if (f32_extra)
        *reinterpret_cast<f32x4*>(f32_extra + (size_t)b * f32_stride + j4) = hv4;
}

// ---------------------------------------------------------------------------
// gru_step (fallback when workspace lacks pre-split weights): one GRU cell,
// grid 64 x 256. Kept verbatim from the previous version.
// ---------------------------------------------------------------------------
__global__ __launch_bounds__(256) void gru_step(
    const ushort_t* __restrict__ A1p,
    const float* __restrict__ emb, const int* __restrict__ tok, int tok_zero,
    const ushort_t* __restrict__ A2p,
    const ushort_t* __restrict__ Wihp, const ushort_t* __restrict__ Whhp,
    const float* __restrict__ Wihf, const float* __restrict__ Whhf,
    const float* __restrict__ bih, const float* __restrict__ bhh,
    const float* __restrict__ h_prev, float* __restrict__ h_out,
    ushort_t* __restrict__ hA_out, ushort_t* __restrict__ hilo_extra,
    float* __restrict__ f32_extra, int f32_stride)
{
    const int tid = threadIdx.x, lane = tid & 63, wv = tid >> 6;
    const int quad = lane >> 4, l16 = lane & 15;
    const int j0 = blockIdx.x * 16, m = wv * 16 + l16, jr = j0 + l16;

    f32x4 accr = {0,0,0,0}, accz = {0,0,0,0}, acci = {0,0,0,0}, acch = {0,0,0,0};

    const float* embrow = nullptr;
    const ushort_t *ah_row = nullptr, *al_row = nullptr;
    if (A1p){ ah_row = A1p + (size_t)m * H; al_row = ah_row + 64 * H; }
    else    { int t = tok_zero ? 0 : tok[m]; embrow = emb + (size_t)t * H; }

    {
        const ushort_t *wrp = nullptr, *wzp = nullptr, *wnp = nullptr;
        const float *wrf = nullptr, *wzf = nullptr, *wnf = nullptr;
        if (Wihp){
            wrp = Wihp + (size_t)jr * H;
            wzp = Wihp + (size_t)(H + jr) * H;
            wnp = Wihp + (size_t)(2 * H + jr) * H;
        } else {
            wrf = Wihf + (size_t)jr * H;
            wzf = Wihf + (size_t)(H + jr) * H;
            wnf = Wihf + (size_t)(2 * H + jr) * H;
        }
        for (int kk = 0; kk < H; kk += 32){
            int ko = kk + quad * 8;
            bf16x8 ah, al;
            if (A1p){ ah = ldb8(ah_row + ko); al = ldb8(al_row + ko); }
            else      split8f(embrow + ko, ah, al);
            bf16x8 wrh, wrl, wzh, wzl, wnh, wnl;
            if (Wihp){
                wrh = ldb8(wrp + ko); wrl = ldb8(wrp + WLO + ko);
                wzh = ldb8(wzp + ko); wzl = ldb8(wzp + WLO + ko);
                wnh = ldb8(wnp + ko); wnl = ldb8(wnp + WLO + ko);
            } else {
                split8f(wrf + ko, wrh, wrl);
                split8f(wzf + ko, wzh, wzl);
                split8f(wnf + ko, wnh, wnl);
            }
            accr = MF(ah, wrh, accr); accr = MF(al, wrh, accr); accr = MF(ah, wrl, accr);
            accz = MF(ah, wzh, accz); accz = MF(al, wzh, accz); accz = MF(ah, wzl, accz);
            acci = MF(ah, wnh, acci); acci = MF(al, wnh, acci); acci = MF(ah, wnl, acci);
        }
    }
    {
        const ushort_t* a2h = A2p + (size_t)m * H;
        const ushort_t* a2l = a2h + 64 * H;
        const ushort_t *wrp = nullptr, *wzp = nullptr, *wnp = nullptr;
        const float *wrf = nullptr, *wzf = nullptr, *wnf = nullptr;
        if (Whhp){
            wrp = Whhp + (size_t)jr * H;
            wzp = Whhp + (size_t)(H + jr) * H;
            wnp = Whhp + (size_t)(2 * H + jr) * H;
        } else {
            wrf = Whhf + (size_t)jr * H;
            wzf = Whhf + (size_t)(H + jr) * H;
            wnf = Whhf + (size_t)(2 * H + jr) * H;
        }
        for (int kk = 0; kk < H; kk += 32){
            int ko = kk + quad * 8;
            bf16x8 ah = ldb8(a2h + ko), al = ldb8(a2l + ko);
            bf16x8 wrh, wrl, wzh, wzl, wnh, wnl;
            if (Whhp){
                wrh = ldb8(wrp + ko); wrl = ldb8(wrp + WLO + ko);
                wzh = ldb8(wzp + ko); wzl = ldb8(wzp + WLO + ko);
                wnh = ldb8(wnp + ko); wnl = ldb8(wnp + WLO + ko);
            } else {
                split8f(wrf + ko, wrh, wrl);
                split8f(wzf + ko, wzh, wzl);
                split8f(wnf + ko, wnh, wnl);
            }
            accr = MF(ah, wrh, accr); accr = MF(al, wrh, accr); accr = MF(ah, wrl, accr);
            accz = MF(ah, wzh, accz); accz = MF(al, wzh, accz); accz = MF(ah, wzl, accz);
            acch = MF(ah, wnh, acch); acch = MF(al, wnh, acch); acch = MF(ah, wnl, acch);
        }
    }

    const float bir = bih[jr],         bhr = bhh[jr];
    const float biz = bih[H + jr],     bhz = bhh[H + jr];
    const float bin = bih[2 * H + jr], bhn = bhh[2 * H + jr];
    #pragma unroll
    for (int reg = 0; reg < 4; ++reg){
        int b = wv * 16 + quad * 4 + reg;
        float r  = sigmf(accr[reg] + bir + bhr);
        float z  = sigmf(accz[reg] + biz + bhz);
        float n  = tanhf(acci[reg] + bin + r * (acch[reg] + bhn));
        float hp = h_prev[b * H + jr];
        float hv = (1.f - z) * n + z * hp;
        h_out[b * H + jr] = hv;
        ushort_t hi = f2bf(hv);
        ushort_t lo = f2bf(hv - bf2f(hi));
        hA_out[b * H + jr] = hi; hA_out[64 * H + b * H + jr] = lo;
        if (hilo_extra){ hilo_extra[b * H + jr] = hi; hilo_extra[64 * H + b * H + jr] = lo; }
        if (f32_extra){ f32_extra[(size_t)b * f32_stride + jr] = hv; }
    }
}

// ---------------------------------------------------------------------------
__global__ __launch_bounds__(256) void vnorm_kernel(const float* __restrict__ enc_out,
                                                    float* __restrict__ v_norm)
{
    const int b = blockIdx.x, tid = threadIdx.x, lane = tid & 63, wv = tid >> 6;
    for (int s = wv; s < SL; s += 4){
        const float* e = enc_out + (size_t)b * SL * H + (size_t)s * H;
        float d = 0.f;
        for (int k = lane; k < H; k += 64){ float v = e[k]; d += v * v; }
        #pragma unroll
        for (int msk = 1; msk < 64; msk <<= 1) d += __shfl_xor(d, msk);
        if (lane == 0) v_norm[b * SL + s] = fmaxf(sqrtf(d), 1e-8f);
    }
}

// ---------------------------------------------------------------------------
// attention: per batch row. scores -> softmax -> context.
// ---------------------------------------------------------------------------
__global__ __launch_bounds__(256) void attn_kernel(
    const float* __restrict__ out_f32, const float* __restrict__ enc_out,
    const float* __restrict__ v_norm, ushort_t* __restrict__ outa,
    float* __restrict__ outa_f, float* __restrict__ attn_out, int step)
{
    const int b = blockIdx.x, tid = threadIdx.x, lane = tid & 63, wv = tid >> 6;
    __shared__ float o_lds[H];
    __shared__ float red[256];
    __shared__ float sc[SL];
    __shared__ float wts[SL];

    float p = 0.f;
    for (int k = tid; k < H; k += 256){ float v = out_f32[b * H + k]; o_lds[k] = v; p += v * v; }
    red[tid] = p; __syncthreads();
    for (int s = 128; s > 0; s >>= 1){ if (tid < s) red[tid] += red[tid + s]; __syncthreads(); }
    float qn = fmaxf(sqrtf(red[0]), 1e-8f);

    for (int s = wv; s < SL; s += 4){
        const float* e = enc_out + (size_t)b * SL * H + (size_t)s * H;
        float d = 0.f;
        for (int k = lane; k < H; k += 64) d += e[k] * o_lds[k];
        #pragma unroll
        for (int msk = 1; msk < 64; msk <<= 1) d += __shfl_xor(d, msk);
        if (lane == 0) sc[s] = d / (v_norm[b * SL + s] * qn);
    }
    __syncthreads();
    if (tid == 0){
        float mx = sc[0];
        for (int s = 1; s < SL; ++s) mx = fmaxf(mx, sc[s]);
        float sum = 0.f;
        for (int s = 0; s < SL; ++s){ float e = expf(sc[s] - mx); wts[s] = e; sum += e; }
        for (int s = 0; s < SL; ++s){
            float w = wts[s] / sum; wts[s] = w;
            attn_out[b * (SL * SL) + step * SL + s] = w;
        }
    }
    __syncthreads();
    for (int k = tid; k < H; k += 256){
        float a = 0.f;
        const float* e = enc_out + (size_t)b * SL * H + k;
        #pragma unroll
        for (int s = 0; s < SL; ++s) a += wts[s] * e[(size_t)s * H];
        float ov = o_lds[k];
        ushort_t oh = f2bf(ov);
        outa[b * 2048 + k]          = oh;
        outa[131072 + b * 2048 + k] = f2bf(ov - bf2f(oh));
        ushort_t ah = f2bf(a);
        outa[b * 2048 + H + k]          = ah;
        outa[131072 + b * 2048 + H + k] = f2bf(a - bf2f(ah));
        outa_f[b * 2048 + k]     = ov;
        outa_f[b * 2048 + H + k] = a;
    }
}

// ---------------------------------------------------------------------------
// fc: logits = [out|a] @ fcW.T + fcb. FC_BLOCKS x FC_ROWS vocab rows.
// ---------------------------------------------------------------------------
__global__ __launch_bounds__(256) void fc_kernel(
    const ushort_t* __restrict__ outa, const ushort_t* __restrict__ fcWhi,
    const float* __restrict__ fcWf, const float* __restrict__ fcb,
    float* __restrict__ vec_out, int step, Partial* __restrict__ parts)
{
    const int tid = threadIdx.x, lane = tid & 63, wv = tid >> 6;
    const int quad = lane >> 4, l16 = lane & 15;
    const int n0 = blockIdx.x * FC_ROWS;
    f32x4 acc[FC_TILES];
    #pragma unroll
    for (int t = 0; t < FC_TILES; ++t) acc[t] = (f32x4){0,0,0,0};
    const ushort_t* arow = outa + (size_t)(wv * 16 + l16) * 2048;

    for (int kk = 0; kk < 2048; kk += 32){
        int ko = kk + quad * 8;
        bf16x8 ah = ldb8(arow + ko);
        bf16x8 al = ldb8(arow + 131072 + ko);
        #pragma unroll
        for (int t = 0; t < FC_TILES; ++t){
            int n = n0 + t * 16 + l16;
            bf16x8 bb = fcWhi ? ldb8(fcWhi + (size_t)n * 2048 + ko)
                              : hi8f(fcWf + (size_t)n * 2048 + ko);
            acc[t] = MF(ah, bb, acc[t]);
            acc[t] = MF(al, bb, acc[t]);
        }
    }
    #pragma unroll
    for (int reg = 0; reg < 4; ++reg){
        int b = wv * 16 + quad * 4 + reg;
        float v1 = -3.4e38f, v2 = -3.4e38f; int i1 = 0x7FFFFFFF, i2 = 0x7FFFFFFF;
        #pragma unroll
        for (int t = 0; t < FC_TILES; ++t){
            int n = n0 + t * 16 + l16;
            float v = acc[t][reg] + fcb[n];
            vec_out[(size_t)b * 1024000 + (size_t)step * 32000 + n] = v;
            t2ins(v1, i1, v2, i2, v, n);
        }
        #pragma unroll
        for (int msk = 1; msk <= 8; msk <<= 1){
            float w1 = __shfl_xor(v1, msk); int j1 = __shfl_xor(i1, msk);
            float w2 = __shfl_xor(v2, msk); int j2 = __shfl_xor(i2, msk);
            t2ins(v1, i1, v2, i2, w1, j1);
            t2ins(v1, i1, v2, i2, w2, j2);
        }
        if (l16 == 0){
            Partial* pp = parts + ((size_t)b * FC_BLOCKS + blockIdx.x) * 2;
            pp[0].v = v1; pp[0].i = i1;
            pp[1].v = v2; pp[1].i = i2;
        }
    }
}

// ---------------------------------------------------------------------------
// pick: per batch row, approx top-8 of NPART partials, exact f64 recheck.
// ---------------------------------------------------------------------------
__global__ __launch_bounds__(256) void pick_kernel(
    const Partial* __restrict__ parts, const float* __restrict__ outa_f,
    const float* __restrict__ fcWf, const float* __restrict__ fcb,
    int* __restrict__ tok)
{
    const int b = blockIdx.x, tid = threadIdx.x;
    __shared__ float pv[2048]; __shared__ int pi[2048];
    __shared__ float rv[256]; __shared__ int ri[256];
    __shared__ int cand[8];
    for (int s = tid; s < 2048; s += 256){
        if (s < NPART){ Partial pp = parts[(size_t)b * NPART + s]; pv[s] = pp.v; pi[s] = pp.i; }
        else { pv[s] = -3.4e38f; pi[s] = 0x7FFFFFFF; }
    }
    __syncthreads();
    for (int r = 0; r < 8; ++r){
        float bvv = -3.4e38f; int bs = tid;
        for (int s = tid; s < 2048; s += 256){
            if (pv[s] > bvv){ bvv = pv[s]; bs = s; }
        }
        rv[tid] = bvv; ri[tid] = bs;
        __syncthreads();
        for (int st = 128; st > 0; st >>= 1){
            if (tid < st && rv[tid + st] > rv[tid]){ rv[tid] = rv[tid + st]; ri[tid] = ri[tid + st]; }
            __syncthreads();
        }
        if (tid == 0){ int sl = ri[0]; cand[r] = pi[sl]; pv[sl] = -3.4e38f; }
        __syncthreads();
    }
    __shared__ double dred[256];
    __shared__ double dbest; __shared__ int dbesti;
    if (tid == 0){ dbest = -1e300; dbesti = 0x7FFFFFFF; }
    __syncthreads();
    for (int c = 0; c < 8; ++c){
        int n = cand[c];
        const float* w = fcWf + (size_t)n * 2048;
        const float* a = outa_f + (size_t)b * 2048;
        double d = 0.0;
        for (int k = tid; k < 2048; k += 256) d += (double)a[k] * (double)w[k];
        dred[tid] = d; __syncthreads();
        for (int st = 128; st > 0; st >>= 1){
            if (tid < st) dred[tid] += dred[tid + st];
            __syncthreads();
        }
        if (tid == 0){
            double tot = dred[0] + (double)fcb[n];
            if (tot > dbest || (tot == dbest && n < dbesti)){ dbest = tot; dbesti = n; }
        }
        __syncthreads();
    }
    if (tid == 0) tok[b] = dbesti;
}

// ---------------------------------------------------------------------------
__global__ __launch_bounds__(256) void fin_kernel(const float* __restrict__ h0f,
                                                  const float* __restrict__ h1f,
                                                  float* __restrict__ dst)
{
    int gid = blockIdx.x * 256 + threadIdx.x;     // 131072
    dst[gid] = (gid < 65536) ? h0f[gid] : h1f[gid - 65536];
}

// ---------------------------------------------------------------------------
extern "C" void kernel_launch(void* const* d_in, const int* in_sizes, int n_in,
                              void* d_out, int out_size, void* d_ws, size_t ws_size,
                              hipStream_t stream)
{
    (void)in_sizes; (void)n_in; (void)out_size;
    const int*   x      = (const int*)d_in[0];
    const float* fr_emb = (const float*)d_in[1];
    const float* en_emb = (const float*)d_in[2];
    const float* eWih   = (const float*)d_in[3];
    const float* eWhh   = (const float*)d_in[4];
    const float* ebih   = (const float*)d_in[5];
    const float* ebhh   = (const float*)d_in[6];
    const float* dWih   = (const float*)d_in[7];
    const float* dWhh   = (const float*)d_in[8];
    const float* dbih   = (const float*)d_in[9];
    const float* dbhh   = (const float*)d_in[10];
    const float* fcWf   = (const float*)d_in[11];
    const float* fcb    = (const float*)d_in[12];
    float* out = (float*)d_out;

    // ---- workspace layout (cursor) ----
    char* ws = (char*)d_ws;
    const size_t GRUW_BYTES = 100663296;      // 8 chunks x [2][3072][1024] bf16
    const size_t SZ_AENC = 8388608, SZ_SEQ0 = 8388608, SZ_HA = 524288,
                 SZ_OUTA = 524288, SZ_ENC = 8388608, SZ_HF = 524288,
                 SZ_OUTAF = 524288, SZ_VN = 8192, SZ_PART = 1048576, SZ_TOK = 4096,
                 SZ_P = 1572864;              // [2][64][3072] f32 partials
    const size_t SMALL_TOTAL = SZ_AENC + SZ_SEQ0 + 2*SZ_HA + SZ_OUTA + SZ_ENC +
                               2*SZ_HF + SZ_OUTAF + SZ_VN + SZ_PART + SZ_TOK + 2*SZ_P;
    bool gru_pre = (ws_size >= GRUW_BYTES + SMALL_TOTAL);
    size_t cur = 0;
    ushort_t* gruW = nullptr;
    if (gru_pre){ gruW = (ushort_t*)(ws + cur); cur += GRUW_BYTES; }
    ushort_t* A_enc = (ushort_t*)(ws + cur); cur += SZ_AENC;
    ushort_t* seq0  = (ushort_t*)(ws + cur); cur += SZ_SEQ0;
    ushort_t* hA0   = (ushort_t*)(ws + cur); cur += SZ_HA;
    ushort_t* hA1   = (ushort_t*)(ws + cur); cur += SZ_HA;
    ushort_t* outa  = (ushort_t*)(ws + cur); cur += SZ_OUTA;
    float*    enc_o = (float*)   (ws + cur); cur += SZ_ENC;
    float*    h0f   = (float*)   (ws + cur); cur += SZ_HF;
    float*    h1f   = (float*)   (ws + cur); cur += SZ_HF;
    float*    outaf = (float*)   (ws + cur); cur += SZ_OUTAF;
    float*    v_nrm = (float*)   (ws + cur); cur += SZ_VN;
    Partial*  parts = (Partial*) (ws + cur); cur += SZ_PART;
    int*      tok   = (int*)     (ws + cur); cur += SZ_TOK;
    float*    Pi    = (float*)   (ws + cur); cur += SZ_P;
    float*    Ph    = (float*)   (ws + cur); cur += SZ_P;
    ushort_t* fcWhi = nullptr;
    if (cur + 131072000 <= ws_size){ fcWhi = (ushort_t*)(ws + cur); cur += 131072000; }

    const size_t CH = 6291456;               // ushorts per weight chunk (2 planes)
    const size_t LYW = 3145728;              // f32 layer stride of (3072,1024)
    const size_t LYB = 3072;

    // ---- prep ----
    if (gru_pre){
        const float* srcs[4] = {eWih, eWhh, dWih, dWhh};
        for (int tns = 0; tns < 4; ++tns)
            for (int l = 0; l < 2; ++l)
                prep_split<<<3072, 256, 0, stream>>>(srcs[tns] + (size_t)l * LYW,
                    gruW + (size_t)(tns * 2 + l) * CH, 786432, WLO);
    }
    if (fcWhi) prep_fcwhi<<<64000, 256, 0, stream>>>(fcWf, fcWhi, 16384000);
    prep_gather<<<2048, 256, 0, stream>>>(x, fr_emb, A_enc);
    prep_zero<<<64, 256, 0, stream>>>(hA0, hA1, h0f, h1f);

    auto WP = [&](int tns, int l) -> const ushort_t* {
        return gru_pre ? gruW + (size_t)(tns * 2 + l) * CH : nullptr;
    };

    if (gru_pre){
        // ---- encoder layer 0 ----
        for (int t = 0; t < 32; ++t){
            gru_gemm<<<256, 256, 0, stream>>>(
                A_enc + (size_t)t * 131072, nullptr, nullptr, 0,
                hA0 + (size_t)(t & 1) * 131072,
                WP(0,0), WP(1,0), Pi, Ph);
            gate_fin<<<64, 256, 0, stream>>>(Pi, Ph, ebih, ebhh,
                h0f + (size_t)(t & 1) * 65536, h0f + (size_t)((t + 1) & 1) * 65536,
                hA0 + (size_t)((t + 1) & 1) * 131072,
                seq0 + (size_t)t * 131072, (float*)nullptr, 0);
        }
        // ---- encoder layer 1 ----
        for (int t = 0; t < 32; ++t){
            gru_gemm<<<256, 256, 0, stream>>>(
                seq0 + (size_t)t * 131072, nullptr, nullptr, 0,
                hA1 + (size_t)(t & 1) * 131072,
                WP(0,1), WP(1,1), Pi, Ph);
            gate_fin<<<64, 256, 0, stream>>>(Pi, Ph, ebih + LYB, ebhh + LYB,
                h1f + (size_t)(t & 1) * 65536, h1f + (size_t)((t + 1) & 1) * 65536,
                hA1 + (size_t)((t + 1) & 1) * 131072,
                (ushort_t*)nullptr, enc_o + (size_t)t * H, SL * H);
        }
    } else {
        for (int t = 0; t < 32; ++t){
            gru_step<<<64, 256, 0, stream>>>(
                A_enc + (size_t)t * 131072, nullptr, nullptr, 0,
                hA0 + (size_t)(t & 1) * 131072,
                WP(0,0), WP(1,0), eWih, eWhh, ebih, ebhh,
                h0f + (size_t)(t & 1) * 65536, h0f + (size_t)((t + 1) & 1) * 65536,
                hA0 + (size_t)((t + 1) & 1) * 131072,
                seq0 + (size_t)t * 131072, (float*)nullptr, 0);
        }
        for (int t = 0; t < 32; ++t){
            gru_step<<<64, 256, 0, stream>>>(
                seq0 + (size_t)t * 131072, nullptr, nullptr, 0,
                hA1 + (size_t)(t & 1) * 131072,
                WP(0,1), WP(1,1), eWih + LYW, eWhh + LYW, ebih + LYB, ebhh + LYB,
                h1f + (size_t)(t & 1) * 65536, h1f + (size_t)((t + 1) & 1) * 65536,
                hA1 + (size_t)((t + 1) & 1) * 131072,
                (ushort_t*)nullptr, enc_o + (size_t)t * H, SL * H);
        }
    }
    vnorm_kernel<<<64, 256, 0, stream>>>(enc_o, v_nrm);

    // ---- greedy decoder ----
    for (int i = 0; i < 32; ++i){
        int p0 = i & 1, p1 = (i + 1) & 1;
        if (gru_pre){
            gru_gemm<<<256, 256, 0, stream>>>(               // layer 0, emb mode
                (const ushort_t*)nullptr, en_emb, tok, (i == 0) ? 1 : 0,
                hA0 + (size_t)p0 * 131072,
                WP(2,0), WP(3,0), Pi, Ph);
            gate_fin<<<64, 256, 0, stream>>>(Pi, Ph, dbih, dbhh,
                h0f + (size_t)p0 * 65536, h0f + (size_t)p1 * 65536,
                hA0 + (size_t)p1 * 131072,
                (ushort_t*)nullptr, (float*)nullptr, 0);
            gru_gemm<<<256, 256, 0, stream>>>(               // layer 1
                hA0 + (size_t)p1 * 131072, nullptr, nullptr, 0,
                hA1 + (size_t)p0 * 131072,
                WP(2,1), WP(3,1), Pi, Ph);
            gate_fin<<<64, 256, 0, stream>>>(Pi, Ph, dbih + LYB, dbhh + LYB,
                h1f + (size_t)p0 * 65536, h1f + (size_t)p1 * 65536,
                hA1 + (size_t)p1 * 131072,
                (ushort_t*)nullptr, (float*)nullptr, 0);
        } else {
            gru_step<<<64, 256, 0, stream>>>(
                (const ushort_t*)nullptr, en_emb, tok, (i == 0) ? 1 : 0,
                hA0 + (size_t)p0 * 131072,
                WP(2,0), WP(3,0), dWih, dWhh, dbih, dbhh,
                h0f + (size_t)p0 * 65536, h0f + (size_t)p1 * 65536,
                hA0 + (size_t)p1 * 131072,
                (ushort_t*)nullptr, (float*)nullptr, 0);
            gru_step<<<64, 256, 0, stream>>>(
                hA0 + (size_t)p1 * 131072, nullptr, nullptr, 0,
                hA1 + (size_t)p0 * 131072,
                WP(2,1), WP(3,1), dWih + LYW, dWhh + LYW, dbih + LYB, dbhh + LYB,
                h1f + (size_t)p0 * 65536, h1f + (size_t)p1 * 65536,
                hA1 + (size_t)p1 * 131072,
                (ushort_t*)nullptr, (float*)nullptr, 0);
        }
        attn_kernel<<<64, 256, 0, stream>>>(
            h1f + (size_t)p1 * 65536, enc_o, v_nrm, outa, outaf,
            out + 65667072u, i);
        fc_kernel<<<FC_BLOCKS, 256, 0, stream>>>(
            outa, fcWhi, fcWf, fcb, out, i, parts);
        if (i < 31)
            pick_kernel<<<64, 256, 0, stream>>>(parts, outaf, fcWf, fcb, tok);
    }
    fin_kernel<<<512, 256, 0, stream>>>(h0f, h1f, out + 65536000u);
}